// Round 15
// baseline (304.517 us; speedup 1.0000x reference)
//
#include <hip/hip_runtime.h>
#include <hip/hip_bf16.h>

typedef __attribute__((ext_vector_type(8))) short short8;
typedef __attribute__((ext_vector_type(4))) float f32x4;
typedef __attribute__((ext_vector_type(2))) float f32x2;
typedef __attribute__((ext_vector_type(4))) unsigned int u32x4;

#define HW_GRID (256 * 512)
// workspace layout (ushort offsets)
#define OFF_W1F   0          // w_pos1 frags           (65536)
#define OFF_W23F  65536      // W23 = W2@W3b frags     (65536)
#define OFF_W3AF  131072     // w_pred1[0:256] frags   (65536)
#define OFF_B3P   196608     // b3' 256 floats         (512 ushorts)
#define OFF_W4F   197120     // w_pred2 frags, 1 nfrag (4096)
#define OFF_GRID  332288     // HWC bf16 grid          (HW_GRID*256)
#define WS_TOTAL_USHORTS (OFF_GRID + (size_t)HW_GRID * 256)

#define ROWS 32              // rows per block; A+B = exactly 32KB

__device__ __forceinline__ unsigned short f2bf(float f) {
  union { float f; unsigned int u; } v; v.f = f;
  unsigned int u = v.u;
  u += 0x7FFFu + ((u >> 16) & 1u);   // round-to-nearest-even
  return (unsigned short)(u >> 16);
}
__device__ __forceinline__ float bf2f(unsigned short b) {
  union { unsigned int u; float f; } v; v.u = ((unsigned int)b) << 16;
  return v.f;
}
// packed pair of bf16 (one u32) -> f32x2 in 2 VALU ops
__device__ __forceinline__ f32x2 bfpair(unsigned int u) {
  union { unsigned int i; float f; } lo, hi;
  lo.i = u << 16; hi.i = u & 0xffff0000u;
  return f32x2{lo.f, hi.f};
}

// MFMA B-fragment layout for 16x16x32: B[k][j] lives at lane=((k%32)/8)*16 + j%16, elem=k%8
__device__ __forceinline__ int frag_off(int k, int j, int nf) {
  int kstep = k >> 5, ke = k & 31;
  int lane = ((ke >> 3) << 4) | (j & 15);
  int e = ke & 7;
  int nfrag = j >> 4;
  return (((kstep * nf + nfrag) << 6) + lane) * 8 + e;
}

// ONE prep dispatch: blocks [0, HW_GRID/32) transpose CHW fp32 -> HWC bf16;
// blocks [HW_GRID/32, +256) build all weight fragments (runs concurrently).
template<bool DOGRID>
__global__ __launch_bounds__(256) void prep_fused(
    const float* __restrict__ grid, const float* __restrict__ w1,
    const float* __restrict__ w2, const float* __restrict__ w3,
    const float* __restrict__ b2, const float* __restrict__ b3,
    const float* __restrict__ w4, unsigned short* __restrict__ ws) {
  __shared__ unsigned short t_lds[32][264];   // +8 pad: spreads LDS banks on read
  if (DOGRID && blockIdx.x < HW_GRID / 32) {
    unsigned short* gh = ws + OFF_GRID;
    const int pix0 = blockIdx.x * 32;
    const int xl = threadIdx.x & 31;          // pixel within block
    const int cg = threadIdx.x >> 5;          // 8 channel groups
#pragma unroll 8
    for (int cc = 0; cc < 32; ++cc) {
      int c = cg * 32 + cc;
      t_lds[xl][c] = f2bf(grid[(size_t)c * HW_GRID + pix0 + xl]);  // coalesced along x
    }
    __syncthreads();
    const int p = threadIdx.x >> 3;           // pixel
    const int s = threadIdx.x & 7;            // 32-ch slice
    unsigned short* dst = gh + ((size_t)(pix0 + p)) * 256 + s * 32;
    const unsigned short* src = &t_lds[p][s * 32];
#pragma unroll
    for (int u = 0; u < 4; ++u)
      *reinterpret_cast<short8*>(dst + u * 8) =
          *reinterpret_cast<const short8*>(src + u * 8);           // coalesced along c
    return;
  }
  // ---- weight blocks
  const int wb = DOGRID ? (int)blockIdx.x - HW_GRID / 32 : (int)blockIdx.x;
  const int idx = wb * 256 + threadIdx.x;     // 0..65535
  const int k = idx >> 8, j = idx & 255;
  // W23[k][j] = sum_i W2[k][i] * W3[256+i][j]  (ILP-4 accumulators)
  const float* w2r = w2 + k * 512;
  const float* w3b = w3 + 256 * 256 + j;
  float s0 = 0.f, s1 = 0.f, s2 = 0.f, s3 = 0.f;
#pragma unroll 4
  for (int i = 0; i < 512; i += 4) {
    s0 += w2r[i]     * w3b[(size_t)i * 256];
    s1 += w2r[i + 1] * w3b[(size_t)(i + 1) * 256];
    s2 += w2r[i + 2] * w3b[(size_t)(i + 2) * 256];
    s3 += w2r[i + 3] * w3b[(size_t)(i + 3) * 256];
  }
  ws[OFF_W23F + frag_off(k, j, 16)] = f2bf((s0 + s1) + (s2 + s3));
  ws[OFF_W1F + frag_off(k, j, 16)] = f2bf(k < 231 ? w1[k * 256 + j] : 0.0f);
  ws[OFF_W3AF + frag_off(k, j, 16)] = f2bf(w3[k * 256 + j]);   // geo rows 0..255
  if (idx < 1024) {                           // w_pred2 256x4 (cols 4..15 unused)
    int kk = idx >> 2, jj = idx & 3;
    ws[OFF_W4F + frag_off(kk, jj, 1)] = f2bf(w4[idx]);
  }
  if (idx < 256) {                            // b3' = b3 + b2 @ W3b
    float t0 = b3[idx], t1 = 0.f;
    for (int i = 0; i < 512; i += 2) {
      t0 += b2[i] * w3[(size_t)(256 + i) * 256 + idx];
      t1 += b2[i + 1] * w3[(size_t)(257 + i) * 256 + idx];
    }
    ((float*)(ws + OFF_B3P))[idx] = t0 + t1;
  }
}

// XOR-swizzled LDS index (ushort units). Kills 32-way bank conflict on
// stride-512B row-major ds_read_b128 (Guideline 4 / T2).
__device__ __forceinline__ int swz(int row, int col) {
  int byte = (col << 1) ^ ((row & 7) << 4);
  return row * 256 + (byte >> 1);
}

// A-tile (ROWS x 256, bf16, swizzled LDS) @ B (frag-order) -> acc[2][NW], K=256
template<int NW>
__device__ __forceinline__ void gemm_mfma(const unsigned short* __restrict__ At,
                                          const short8* __restrict__ Bf,
                                          int nftot, int nf0, int lane,
                                          f32x4 acc[2][NW]) {
  const int arow = lane & 15;
  const int acol = (lane >> 4) << 3;
  for (int ks = 0; ks < 8; ++ks) {
    short8 a[2];
#pragma unroll
    for (int m = 0; m < 2; ++m)
      a[m] = *reinterpret_cast<const short8*>(&At[swz(m * 16 + arow, ks * 32 + acol)]);
#pragma unroll
    for (int n = 0; n < NW; ++n) {
      short8 b = Bf[(ks * nftot + nf0 + n) * 64 + lane];
#pragma unroll
      for (int m = 0; m < 2; ++m)
        acc[m][n] = __builtin_amdgcn_mfma_f32_16x16x32_bf16(a[m], b, acc[m][n], 0, 0, 0);
    }
  }
}

// C layout: col = lane&15, row = (lane>>4)*4 + reg  [measured m89/m91]
// Packed t-pairs: pk add/max + one cvt per pair.
template<int NW, bool RELU>
__device__ __forceinline__ void epilogue(f32x4 acc[2][NW], const float* __restrict__ bias,
                                         int bcol0, unsigned short* __restrict__ dst,
                                         int dcol0, int lane) {
  const int jlo = lane & 15;
  const int rhi = (lane >> 4) << 2;
#pragma unroll
  for (int n = 0; n < NW; ++n) {
    float bv = bias[bcol0 + n * 16 + jlo];
#pragma unroll
    for (int m = 0; m < 2; ++m) {
#pragma unroll
      for (int t = 0; t < 4; t += 2) {
        f32x2 v = f32x2{acc[m][n][t], acc[m][n][t + 1]} + bv;
        if (RELU) { v[0] = fmaxf(v[0], 0.0f); v[1] = fmaxf(v[1], 0.0f); }
        union { __hip_bfloat162 b; unsigned int u; } cv;
        cv.b = __float22bfloat162_rn(float2{v[0], v[1]});
        dst[swz(m * 16 + rhi + t,     dcol0 + n * 16 + jlo)] = (unsigned short)cv.u;
        dst[swz(m * 16 + rhi + t + 1, dcol0 + n * 16 + jlo)] = (unsigned short)(cv.u >> 16);
      }
    }
  }
}

// blend 8 channels from 4 corners -> bf16x8 (packed dual-fp32 math)
__device__ __forceinline__ short8 blend8(short8 a, short8 b, short8 c, short8 d,
                                         float w00, float w01, float w10, float w11) {
  u32x4 au = *reinterpret_cast<u32x4*>(&a);
  u32x4 bu = *reinterpret_cast<u32x4*>(&b);
  u32x4 cu = *reinterpret_cast<u32x4*>(&c);
  u32x4 du = *reinterpret_cast<u32x4*>(&d);
  short8 res;
  __hip_bfloat162* rp = reinterpret_cast<__hip_bfloat162*>(&res);
#pragma unroll
  for (int p = 0; p < 4; ++p) {
    f32x2 v = bfpair(au[p]) * w00 + bfpair(bu[p]) * w01 +
              bfpair(cu[p]) * w10 + bfpair(du[p]) * w11;
    rp[p] = __float22bfloat162_rn(float2{v[0], v[1]});
  }
  return res;
}

template<bool HWC>
__global__ __launch_bounds__(256, 4) void fused_decoder(
    const float* __restrict__ grid, const float* __restrict__ sgrad,
    const float* __restrict__ qpos, const float* __restrict__ quinf,
    const float* __restrict__ qsdf, const float* __restrict__ qnrm,
    const float* __restrict__ qflow,
    const float* __restrict__ b1, const float* __restrict__ b4v,
    const unsigned short* __restrict__ wsh,
    float* __restrict__ out, int N) {
  // A: ff -> geo -> h2.  B: h.  Exactly 32KB.
  __shared__ __align__(16) unsigned short A_lds[ROWS * 256];   // 16 KB
  __shared__ __align__(16) unsigned short B_lds[ROWS * 256];   // 16 KB

  const int tid = threadIdx.x;
  const int lane = tid & 63;
  const int wid = tid >> 6;           // 4 waves
  const int row0 = blockIdx.x * ROWS;
  const short8* WF1  = (const short8*)(wsh + OFF_W1F);
  const short8* WF23 = (const short8*)(wsh + OFF_W23F);
  const short8* WF3A = (const short8*)(wsh + OFF_W3AF);
  const short8* WF4  = (const short8*)(wsh + OFF_W4F);
  const float*  b3p  = (const float*)(wsh + OFF_B3P);
  const unsigned short* gh = wsh + OFF_GRID;

  // ---- Phase 0: EVERY thread computes its row's coords AND all 11 features
  //      (uniform loads — same-line broadcast across the row's 8 threads; no
  //      divergent loads, no id_lds).  Holds corners 0/1 complete (T14).
  const int r = tid >> 3;            // gather row of this thread
  const int s = tid & 7;             // 32-channel slice / store-owner id
  int qoff[4];
  float wq00, wq01, wq10, wq11;
  {
    int g = row0 + r; if (g >= N) g = N - 1;
    float px = qpos[g * 2], py = qpos[g * 2 + 1];
    float xn = 2.0f * (px - (-2.0f)) / 6.0f - 1.0f;
    float yn = 2.0f * (py - (-1.5f)) / 3.0f - 1.0f;
    xn = fminf(fmaxf(xn, -1.0f), 1.0f);
    yn = fminf(fmaxf(yn, -1.0f), 1.0f);
    float ix = (xn + 1.0f) * 0.5f * 511.0f;
    float iy = (yn + 1.0f) * 0.5f * 255.0f;
    float x0f = floorf(ix), y0f = floorf(iy);
    float wx = ix - x0f, wy = iy - y0f;
    int x0 = (int)fminf(fmaxf(x0f, 0.0f), 511.0f);
    int x1 = (int)fminf(fmaxf(x0f + 1.0f, 0.0f), 511.0f);
    int y0 = (int)fminf(fmaxf(y0f, 0.0f), 255.0f);
    int y1 = (int)fminf(fmaxf(y0f + 1.0f, 0.0f), 255.0f);
    qoff[0] = y0 * 512 + x0; qoff[1] = y0 * 512 + x1;
    qoff[2] = y1 * 512 + x0; qoff[3] = y1 * 512 + x1;
    wq00 = (1.0f - wx) * (1.0f - wy); wq01 = wx * (1.0f - wy);
    wq10 = (1.0f - wx) * wy;          wq11 = wx * wy;

    // issue corner-0/1 gather loads NOW (full cache lines; consumed after GEMM1)
    short8 pre0[4], pre1[4];
    if (HWC) {
      const unsigned short* p0 = gh + (size_t)qoff[0] * 256 + s * 32;
      const unsigned short* p1 = gh + (size_t)qoff[1] * 256 + s * 32;
#pragma unroll
      for (int u = 0; u < 4; ++u) pre0[u] = *reinterpret_cast<const short8*>(p0 + u * 8);
#pragma unroll
      for (int u = 0; u < 4; ++u) pre1[u] = *reinterpret_cast<const short8*>(p1 + u * 8);
    }

    // ---- all 11 features, uniform control flow (broadcast loads)
    float f2v = quinf[g * 2], f3v = quinf[g * 2 + 1], f4v = qsdf[g];
    float f5v = wq00 * sgrad[qoff[0]] + wq01 * sgrad[qoff[1]] +
                wq10 * sgrad[qoff[2]] + wq11 * sgrad[qoff[3]];
    const float* s1p = sgrad + HW_GRID;
    float f6v = wq00 * s1p[qoff[0]] + wq01 * s1p[qoff[1]] +
                wq10 * s1p[qoff[2]] + wq11 * s1p[qoff[3]];
    float f7v = qnrm[g * 2], f8v = qnrm[g * 2 + 1];
    float f9v = qflow[g * 2], f10v = qflow[g * 2 + 1];

    // identity cols: col c owned by thread (c&7) — predicated stores only
#define IDW(c, fvc) if (((c) & 7) == s) A_lds[swz(r, (c))] = f2bf(fvc);
    IDW(0, px) IDW(1, py) IDW(2, f2v) IDW(3, f3v) IDW(4, f4v) IDW(5, f5v)
    IDW(6, f6v) IDW(7, f7v) IDW(8, f8v) IDW(9, f9v) IDW(10, f10v)
#undef IDW

    // fourier: pair (i,k) owned by thread ((10i+k)&7): k = k0 = (s-2i)&7, and
    // k0+8 when k0<2.  sin(v*pi*2^k) = sin(2pi * v*2^(k-1)); exact pow2 scale,
    // fract exact -> only pi_f32-rounding-class arg error (~7e-4), under bf16.
#define FOUR(i, fvi) { \
      int k0 = (s - 2 * (i)) & 7; \
      float rev = (fvi) * 0.5f * (float)(1 << k0); \
      float fr = rev - floorf(rev); \
      A_lds[swz(r, 11 + (i) * 10 + k0)] = f2bf(__builtin_amdgcn_sinf(fr)); \
      A_lds[swz(r, 121 + (i) * 10 + k0)] = f2bf(__builtin_amdgcn_cosf(fr)); \
      if (k0 < 2) { \
        float rev2 = rev * 256.0f; \
        float fr2 = rev2 - floorf(rev2); \
        A_lds[swz(r, 11 + (i) * 10 + k0 + 8)] = f2bf(__builtin_amdgcn_sinf(fr2)); \
        A_lds[swz(r, 121 + (i) * 10 + k0 + 8)] = f2bf(__builtin_amdgcn_cosf(fr2)); \
      } }
    FOUR(0, px) FOUR(1, py) FOUR(2, f2v) FOUR(3, f3v) FOUR(4, f4v) FOUR(5, f5v)
    FOUR(6, f6v) FOUR(7, f7v) FOUR(8, f8v) FOUR(9, f9v) FOUR(10, f10v)
#undef FOUR

    // K-pad cols 231..255 (25 cols spread over 8 threads)
    A_lds[swz(r, 231 + s)] = 0;
    A_lds[swz(r, 239 + s)] = 0;
    A_lds[swz(r, 247 + s)] = 0;
    if (s == 0) A_lds[swz(r, 255)] = 0;
    __syncthreads();

    // ---- G1: acc1 = ff @ W1 ; E1: h = relu(+b1) -> B
    {
      f32x4 acc1[2][4] = {};
      gemm_mfma<4>(A_lds, WF1, 16, wid * 4, lane, acc1);
      epilogue<4, true>(acc1, b1, wid * 64, B_lds, wid * 64, lane);
    }
    __syncthreads();   // ff reads done; h fully written

    // ---- GA: load corners 2,3 (full lines), blend all 4 -> geo into A (ff dead)
    if (HWC) {
      short8 c2[4], c3[4];
      const unsigned short* p2 = gh + (size_t)qoff[2] * 256 + s * 32;
      const unsigned short* p3 = gh + (size_t)qoff[3] * 256 + s * 32;
#pragma unroll
      for (int u = 0; u < 4; ++u) c2[u] = *reinterpret_cast<const short8*>(p2 + u * 8);
#pragma unroll
      for (int u = 0; u < 4; ++u) c3[u] = *reinterpret_cast<const short8*>(p3 + u * 8);
#pragma unroll
      for (int u = 0; u < 4; ++u)
        *reinterpret_cast<short8*>(&A_lds[swz(r, s * 32 + u * 8)]) =
            blend8(pre0[u], pre1[u], c2[u], c3[u], wq00, wq01, wq10, wq11);
    } else {
      const int c0 = s << 5;
      const float* gp = grid + (size_t)c0 * HW_GRID;
#pragma unroll 4
      for (int cc = 0; cc < 32; ++cc, gp += HW_GRID) {
        float v = wq00 * gp[qoff[0]] + wq01 * gp[qoff[1]] +
                  wq10 * gp[qoff[2]] + wq11 * gp[qoff[3]];
        A_lds[swz(r, c0 + cc)] = f2bf(v);
      }
    }
  }
  __syncthreads();

  // ---- G3: acc3 = geo@W3a + h@W23 ; E3: h2 = relu(+b3') -> A
  {
    f32x4 acc3[2][4] = {};
    gemm_mfma<4>(A_lds, WF3A, 16, wid * 4, lane, acc3);   // geo part
    gemm_mfma<4>(B_lds, WF23, 16, wid * 4, lane, acc3);   // h @ (W2@W3b)
    __syncthreads();                                      // drain all reads of A,B
    epilogue<4, true>(acc3, b3p, wid * 64, A_lds, wid * 64, lane);  // h2 -> A
  }
  __syncthreads();

  // ---- P4: out = h2 @ w_pred2 + b4 via MFMA (waves 0,1: rows m = wid; cols 4..15 junk)
  if (wid < 2) {
    f32x4 acc4 = {0.0f, 0.0f, 0.0f, 0.0f};
    const int arow = lane & 15;
    const int acol = (lane >> 4) << 3;
#pragma unroll
    for (int ks = 0; ks < 8; ++ks) {
      short8 a = *reinterpret_cast<const short8*>(&A_lds[swz(wid * 16 + arow, ks * 32 + acol)]);
      short8 b = WF4[ks * 64 + lane];
      acc4 = __builtin_amdgcn_mfma_f32_16x16x32_bf16(a, b, acc4, 0, 0, 0);
    }
    const int jlo = lane & 15;
    const int rhi = (lane >> 4) << 2;
    if (jlo < 4) {
      float bv = b4v[jlo];
#pragma unroll
      for (int t = 0; t < 4; ++t) {
        int g = row0 + wid * 16 + rhi + t;
        if (g < N) out[g * 4 + jlo] = acc4[t] + bv;
      }
    }
  }
}

extern "C" void kernel_launch(void* const* d_in, const int* in_sizes, int n_in,
                              void* d_out, int out_size, void* d_ws, size_t ws_size,
                              hipStream_t stream) {
  const float* grid  = (const float*)d_in[0];
  const float* sgrad = (const float*)d_in[1];
  const float* qpos  = (const float*)d_in[2];
  const float* quinf = (const float*)d_in[3];
  const float* qsdf  = (const float*)d_in[4];
  const float* qnrm  = (const float*)d_in[5];
  const float* qflow = (const float*)d_in[6];
  const float* w1 = (const float*)d_in[7];
  const float* b1 = (const float*)d_in[8];
  const float* w2 = (const float*)d_in[9];
  const float* b2 = (const float*)d_in[10];
  const float* w3 = (const float*)d_in[11];
  const float* b3 = (const float*)d_in[12];
  const float* w4 = (const float*)d_in[13];
  const float* b4 = (const float*)d_in[14];
  float* out = (float*)d_out;
  unsigned short* wsh = (unsigned short*)d_ws;

  const int N = in_sizes[2] / 2;  // 200000
  const bool hwc = ws_size >= WS_TOTAL_USHORTS * 2;

  if (hwc) {
    prep_fused<true><<<HW_GRID / 32 + 256, 256, 0, stream>>>(
        grid, w1, w2, w3, b2, b3, w4, wsh);
    fused_decoder<true><<<(N + ROWS - 1) / ROWS, 256, 0, stream>>>(
        grid, sgrad, qpos, quinf, qsdf, qnrm, qflow,
        b1, b4, wsh, out, N);
  } else {
    prep_fused<false><<<256, 256, 0, stream>>>(
        grid, w1, w2, w3, b2, b3, w4, wsh);
    fused_decoder<false><<<(N + ROWS - 1) / ROWS, 256, 0, stream>>>(
        grid, sgrad, qpos, quinf, qsdf, qnrm, qflow,
        b1, b4, wsh, out, N);
  }
}

// Round 16
// 214.790 us; speedup vs baseline: 1.4177x; 1.4177x over previous
//
#include <hip/hip_runtime.h>
#include <hip/hip_bf16.h>

typedef __attribute__((ext_vector_type(8))) short short8;
typedef __attribute__((ext_vector_type(4))) float f32x4;
typedef __attribute__((ext_vector_type(2))) float f32x2;
typedef __attribute__((ext_vector_type(4))) unsigned int u32x4;

#define HW_GRID (256 * 512)
// workspace layout (ushort offsets)
#define OFF_W1F   0          // w_pos1 frags           (65536)
#define OFF_W23F  65536      // W23 = W2@W3b frags     (65536)
#define OFF_W3AF  131072     // w_pred1[0:256] frags   (65536)
#define OFF_B3P   196608     // b3' 256 floats         (512 ushorts)
#define OFF_W4F   197120     // w_pred2 frags, 1 nfrag (4096)
#define OFF_GRID  332288     // HWC bf16 grid          (HW_GRID*256)
#define WS_TOTAL_USHORTS (OFF_GRID + (size_t)HW_GRID * 256)

#define ROWS 32              // rows per block; A+B = exactly 32KB

__device__ __forceinline__ unsigned short f2bf(float f) {
  union { float f; unsigned int u; } v; v.f = f;
  unsigned int u = v.u;
  u += 0x7FFFu + ((u >> 16) & 1u);   // round-to-nearest-even
  return (unsigned short)(u >> 16);
}
__device__ __forceinline__ float bf2f(unsigned short b) {
  union { unsigned int u; float f; } v; v.u = ((unsigned int)b) << 16;
  return v.f;
}
// packed pair of bf16 (one u32) -> f32x2 in 2 VALU ops
__device__ __forceinline__ f32x2 bfpair(unsigned int u) {
  union { unsigned int i; float f; } lo, hi;
  lo.i = u << 16; hi.i = u & 0xffff0000u;
  return f32x2{lo.f, hi.f};
}

// MFMA B-fragment layout for 16x16x32: B[k][j] lives at lane=((k%32)/8)*16 + j%16, elem=k%8
__device__ __forceinline__ int frag_off(int k, int j, int nf) {
  int kstep = k >> 5, ke = k & 31;
  int lane = ((ke >> 3) << 4) | (j & 15);
  int e = ke & 7;
  int nfrag = j >> 4;
  return (((kstep * nf + nfrag) << 6) + lane) * 8 + e;
}

// ONE prep dispatch: blocks [0, HW_GRID/32) transpose CHW fp32 -> HWC bf16;
// blocks [HW_GRID/32, +256) build all weight fragments (runs concurrently).
template<bool DOGRID>
__global__ __launch_bounds__(256) void prep_fused(
    const float* __restrict__ grid, const float* __restrict__ w1,
    const float* __restrict__ w2, const float* __restrict__ w3,
    const float* __restrict__ b2, const float* __restrict__ b3,
    const float* __restrict__ w4, unsigned short* __restrict__ ws) {
  __shared__ unsigned short t_lds[32][264];   // +8 pad: spreads LDS banks on read
  if (DOGRID && blockIdx.x < HW_GRID / 32) {
    unsigned short* gh = ws + OFF_GRID;
    const int pix0 = blockIdx.x * 32;
    const int xl = threadIdx.x & 31;          // pixel within block
    const int cg = threadIdx.x >> 5;          // 8 channel groups
#pragma unroll 8
    for (int cc = 0; cc < 32; ++cc) {
      int c = cg * 32 + cc;
      t_lds[xl][c] = f2bf(grid[(size_t)c * HW_GRID + pix0 + xl]);  // coalesced along x
    }
    __syncthreads();
    const int p = threadIdx.x >> 3;           // pixel
    const int s = threadIdx.x & 7;            // 32-ch slice
    unsigned short* dst = gh + ((size_t)(pix0 + p)) * 256 + s * 32;
    const unsigned short* src = &t_lds[p][s * 32];
#pragma unroll
    for (int u = 0; u < 4; ++u)
      *reinterpret_cast<short8*>(dst + u * 8) =
          *reinterpret_cast<const short8*>(src + u * 8);           // coalesced along c
    return;
  }
  // ---- weight blocks
  const int wb = DOGRID ? (int)blockIdx.x - HW_GRID / 32 : (int)blockIdx.x;
  const int idx = wb * 256 + threadIdx.x;     // 0..65535
  const int k = idx >> 8, j = idx & 255;
  // W23[k][j] = sum_i W2[k][i] * W3[256+i][j]  (ILP-4 accumulators)
  const float* w2r = w2 + k * 512;
  const float* w3b = w3 + 256 * 256 + j;
  float s0 = 0.f, s1 = 0.f, s2 = 0.f, s3 = 0.f;
#pragma unroll 4
  for (int i = 0; i < 512; i += 4) {
    s0 += w2r[i]     * w3b[(size_t)i * 256];
    s1 += w2r[i + 1] * w3b[(size_t)(i + 1) * 256];
    s2 += w2r[i + 2] * w3b[(size_t)(i + 2) * 256];
    s3 += w2r[i + 3] * w3b[(size_t)(i + 3) * 256];
  }
  ws[OFF_W23F + frag_off(k, j, 16)] = f2bf((s0 + s1) + (s2 + s3));
  ws[OFF_W1F + frag_off(k, j, 16)] = f2bf(k < 231 ? w1[k * 256 + j] : 0.0f);
  ws[OFF_W3AF + frag_off(k, j, 16)] = f2bf(w3[k * 256 + j]);   // geo rows 0..255
  if (idx < 1024) {                           // w_pred2 256x4 (cols 4..15 unused)
    int kk = idx >> 2, jj = idx & 3;
    ws[OFF_W4F + frag_off(kk, jj, 1)] = f2bf(w4[idx]);
  }
  if (idx < 256) {                            // b3' = b3 + b2 @ W3b
    float t0 = b3[idx], t1 = 0.f;
    for (int i = 0; i < 512; i += 2) {
      t0 += b2[i] * w3[(size_t)(256 + i) * 256 + idx];
      t1 += b2[i + 1] * w3[(size_t)(257 + i) * 256 + idx];
    }
    ((float*)(ws + OFF_B3P))[idx] = t0 + t1;
  }
}

// XOR-swizzled LDS index (ushort units). Kills 32-way bank conflict on
// stride-512B row-major ds_read_b128 (Guideline 4 / T2).
__device__ __forceinline__ int swz(int row, int col) {
  int byte = (col << 1) ^ ((row & 7) << 4);
  return row * 256 + (byte >> 1);
}

// A-tile (ROWS x 256, bf16, swizzled LDS) @ B (frag-order) -> acc[2][NW], K=256
template<int NW>
__device__ __forceinline__ void gemm_mfma(const unsigned short* __restrict__ At,
                                          const short8* __restrict__ Bf,
                                          int nftot, int nf0, int lane,
                                          f32x4 acc[2][NW]) {
  const int arow = lane & 15;
  const int acol = (lane >> 4) << 3;
  for (int ks = 0; ks < 8; ++ks) {
    short8 a[2];
#pragma unroll
    for (int m = 0; m < 2; ++m)
      a[m] = *reinterpret_cast<const short8*>(&At[swz(m * 16 + arow, ks * 32 + acol)]);
#pragma unroll
    for (int n = 0; n < NW; ++n) {
      short8 b = Bf[(ks * nftot + nf0 + n) * 64 + lane];
#pragma unroll
      for (int m = 0; m < 2; ++m)
        acc[m][n] = __builtin_amdgcn_mfma_f32_16x16x32_bf16(a[m], b, acc[m][n], 0, 0, 0);
    }
  }
}

// C layout: col = lane&15, row = (lane>>4)*4 + reg  [measured m89/m91]
// Packed t-pairs: pk add/max + one cvt per pair.
template<int NW, bool RELU>
__device__ __forceinline__ void epilogue(f32x4 acc[2][NW], const float* __restrict__ bias,
                                         int bcol0, unsigned short* __restrict__ dst,
                                         int dcol0, int lane) {
  const int jlo = lane & 15;
  const int rhi = (lane >> 4) << 2;
#pragma unroll
  for (int n = 0; n < NW; ++n) {
    float bv = bias[bcol0 + n * 16 + jlo];
#pragma unroll
    for (int m = 0; m < 2; ++m) {
#pragma unroll
      for (int t = 0; t < 4; t += 2) {
        f32x2 v = f32x2{acc[m][n][t], acc[m][n][t + 1]} + bv;
        if (RELU) { v[0] = fmaxf(v[0], 0.0f); v[1] = fmaxf(v[1], 0.0f); }
        union { __hip_bfloat162 b; unsigned int u; } cv;
        cv.b = __float22bfloat162_rn(float2{v[0], v[1]});
        dst[swz(m * 16 + rhi + t,     dcol0 + n * 16 + jlo)] = (unsigned short)cv.u;
        dst[swz(m * 16 + rhi + t + 1, dcol0 + n * 16 + jlo)] = (unsigned short)(cv.u >> 16);
      }
    }
  }
}

// blend 8 channels from 4 corners -> bf16x8 (packed dual-fp32 math)
__device__ __forceinline__ short8 blend8(short8 a, short8 b, short8 c, short8 d,
                                         float w00, float w01, float w10, float w11) {
  u32x4 au = *reinterpret_cast<u32x4*>(&a);
  u32x4 bu = *reinterpret_cast<u32x4*>(&b);
  u32x4 cu = *reinterpret_cast<u32x4*>(&c);
  u32x4 du = *reinterpret_cast<u32x4*>(&d);
  short8 res;
  __hip_bfloat162* rp = reinterpret_cast<__hip_bfloat162*>(&res);
#pragma unroll
  for (int p = 0; p < 4; ++p) {
    f32x2 v = bfpair(au[p]) * w00 + bfpair(bu[p]) * w01 +
              bfpair(cu[p]) * w10 + bfpair(du[p]) * w11;
    rp[p] = __float22bfloat162_rn(float2{v[0], v[1]});
  }
  return res;
}

template<bool HWC>
__global__ __launch_bounds__(256, 2) void fused_decoder(
    const float* __restrict__ grid, const float* __restrict__ sgrad,
    const float* __restrict__ qpos, const float* __restrict__ quinf,
    const float* __restrict__ qsdf, const float* __restrict__ qnrm,
    const float* __restrict__ qflow,
    const float* __restrict__ b1, const float* __restrict__ b4v,
    const unsigned short* __restrict__ wsh,
    float* __restrict__ out, int N) {
  // A: ff -> geo -> h2.  B: h.  Exactly 32KB.
  __shared__ __align__(16) unsigned short A_lds[ROWS * 256];   // 16 KB
  __shared__ __align__(16) unsigned short B_lds[ROWS * 256];   // 16 KB

  const int tid = threadIdx.x;
  const int lane = tid & 63;
  const int wid = tid >> 6;           // 4 waves
  const int row0 = blockIdx.x * ROWS;
  const short8* WF1  = (const short8*)(wsh + OFF_W1F);
  const short8* WF23 = (const short8*)(wsh + OFF_W23F);
  const short8* WF3A = (const short8*)(wsh + OFF_W3AF);
  const short8* WF4  = (const short8*)(wsh + OFF_W4F);
  const float*  b3p  = (const float*)(wsh + OFF_B3P);
  const unsigned short* gh = wsh + OFF_GRID;

  // ---- Phase 0: EVERY thread computes its row's coords AND all 11 features
  //      (uniform loads — same-line broadcast across the row's 8 threads; no
  //      divergent loads, no id_lds, one barrier instead of two).
  //      Holds corners 0/1 complete (full 64B lines; T14 issue-early).
  const int r = tid >> 3;            // gather row of this thread
  const int s = tid & 7;             // 32-channel slice / store-owner id
  int qoff[4];
  float wq00, wq01, wq10, wq11;
  {
    int g = row0 + r; if (g >= N) g = N - 1;
    float px = qpos[g * 2], py = qpos[g * 2 + 1];
    float xn = 2.0f * (px - (-2.0f)) / 6.0f - 1.0f;
    float yn = 2.0f * (py - (-1.5f)) / 3.0f - 1.0f;
    xn = fminf(fmaxf(xn, -1.0f), 1.0f);
    yn = fminf(fmaxf(yn, -1.0f), 1.0f);
    float ix = (xn + 1.0f) * 0.5f * 511.0f;
    float iy = (yn + 1.0f) * 0.5f * 255.0f;
    float x0f = floorf(ix), y0f = floorf(iy);
    float wx = ix - x0f, wy = iy - y0f;
    int x0 = (int)fminf(fmaxf(x0f, 0.0f), 511.0f);
    int x1 = (int)fminf(fmaxf(x0f + 1.0f, 0.0f), 511.0f);
    int y0 = (int)fminf(fmaxf(y0f, 0.0f), 255.0f);
    int y1 = (int)fminf(fmaxf(y0f + 1.0f, 0.0f), 255.0f);
    qoff[0] = y0 * 512 + x0; qoff[1] = y0 * 512 + x1;
    qoff[2] = y1 * 512 + x0; qoff[3] = y1 * 512 + x1;
    wq00 = (1.0f - wx) * (1.0f - wy); wq01 = wx * (1.0f - wy);
    wq10 = (1.0f - wx) * wy;          wq11 = wx * wy;

    // issue corner-0/1 gather loads NOW (full cache lines; consumed after GEMM1)
    short8 pre0[4], pre1[4];
    if (HWC) {
      const unsigned short* p0 = gh + (size_t)qoff[0] * 256 + s * 32;
      const unsigned short* p1 = gh + (size_t)qoff[1] * 256 + s * 32;
#pragma unroll
      for (int u = 0; u < 4; ++u) pre0[u] = *reinterpret_cast<const short8*>(p0 + u * 8);
#pragma unroll
      for (int u = 0; u < 4; ++u) pre1[u] = *reinterpret_cast<const short8*>(p1 + u * 8);
    }

    // ---- all 11 features, uniform control flow (broadcast loads)
    float f2v = quinf[g * 2], f3v = quinf[g * 2 + 1], f4v = qsdf[g];
    float f5v = wq00 * sgrad[qoff[0]] + wq01 * sgrad[qoff[1]] +
                wq10 * sgrad[qoff[2]] + wq11 * sgrad[qoff[3]];
    const float* s1p = sgrad + HW_GRID;
    float f6v = wq00 * s1p[qoff[0]] + wq01 * s1p[qoff[1]] +
                wq10 * s1p[qoff[2]] + wq11 * s1p[qoff[3]];
    float f7v = qnrm[g * 2], f8v = qnrm[g * 2 + 1];
    float f9v = qflow[g * 2], f10v = qflow[g * 2 + 1];

    // identity cols: col c owned by thread (c&7) — predicated stores only
#define IDW(c, fvc) if (((c) & 7) == s) A_lds[swz(r, (c))] = f2bf(fvc);
    IDW(0, px) IDW(1, py) IDW(2, f2v) IDW(3, f3v) IDW(4, f4v) IDW(5, f5v)
    IDW(6, f6v) IDW(7, f7v) IDW(8, f8v) IDW(9, f9v) IDW(10, f10v)
#undef IDW

    // fourier: pair (i,k) owned by thread ((10i+k)&7): k = k0 = (s-2i)&7, and
    // k0+8 when k0<2.  sin(v*pi*2^k) = sin(2pi * v*2^(k-1)); exact pow2 scale,
    // fract exact -> only pi_f32-rounding-class arg error (~7e-4), under bf16.
#define FOUR(i, fvi) { \
      int k0 = (s - 2 * (i)) & 7; \
      float rev = (fvi) * 0.5f * (float)(1 << k0); \
      float fr = rev - floorf(rev); \
      A_lds[swz(r, 11 + (i) * 10 + k0)] = f2bf(__builtin_amdgcn_sinf(fr)); \
      A_lds[swz(r, 121 + (i) * 10 + k0)] = f2bf(__builtin_amdgcn_cosf(fr)); \
      if (k0 < 2) { \
        float rev2 = rev * 256.0f; \
        float fr2 = rev2 - floorf(rev2); \
        A_lds[swz(r, 11 + (i) * 10 + k0 + 8)] = f2bf(__builtin_amdgcn_sinf(fr2)); \
        A_lds[swz(r, 121 + (i) * 10 + k0 + 8)] = f2bf(__builtin_amdgcn_cosf(fr2)); \
      } }
    FOUR(0, px) FOUR(1, py) FOUR(2, f2v) FOUR(3, f3v) FOUR(4, f4v) FOUR(5, f5v)
    FOUR(6, f6v) FOUR(7, f7v) FOUR(8, f8v) FOUR(9, f9v) FOUR(10, f10v)
#undef FOUR

    // K-pad cols 231..255 (25 cols spread over 8 threads)
    A_lds[swz(r, 231 + s)] = 0;
    A_lds[swz(r, 239 + s)] = 0;
    A_lds[swz(r, 247 + s)] = 0;
    if (s == 0) A_lds[swz(r, 255)] = 0;
    __syncthreads();

    // ---- G1: acc1 = ff @ W1 ; E1: h = relu(+b1) -> B
    {
      f32x4 acc1[2][4] = {};
      gemm_mfma<4>(A_lds, WF1, 16, wid * 4, lane, acc1);
      epilogue<4, true>(acc1, b1, wid * 64, B_lds, wid * 64, lane);
    }
    __syncthreads();   // ff reads done; h fully written

    // ---- GA: load corners 2,3 (full lines), blend all 4 -> geo into A (ff dead)
    if (HWC) {
      short8 c2[4], c3[4];
      const unsigned short* p2 = gh + (size_t)qoff[2] * 256 + s * 32;
      const unsigned short* p3 = gh + (size_t)qoff[3] * 256 + s * 32;
#pragma unroll
      for (int u = 0; u < 4; ++u) c2[u] = *reinterpret_cast<const short8*>(p2 + u * 8);
#pragma unroll
      for (int u = 0; u < 4; ++u) c3[u] = *reinterpret_cast<const short8*>(p3 + u * 8);
#pragma unroll
      for (int u = 0; u < 4; ++u)
        *reinterpret_cast<short8*>(&A_lds[swz(r, s * 32 + u * 8)]) =
            blend8(pre0[u], pre1[u], c2[u], c3[u], wq00, wq01, wq10, wq11);
    } else {
      const int c0 = s << 5;
      const float* gp = grid + (size_t)c0 * HW_GRID;
#pragma unroll 4
      for (int cc = 0; cc < 32; ++cc, gp += HW_GRID) {
        float v = wq00 * gp[qoff[0]] + wq01 * gp[qoff[1]] +
                  wq10 * gp[qoff[2]] + wq11 * gp[qoff[3]];
        A_lds[swz(r, c0 + cc)] = f2bf(v);
      }
    }
  }
  __syncthreads();

  // ---- G3: acc3 = geo@W3a + h@W23 ; E3: h2 = relu(+b3') -> A
  {
    f32x4 acc3[2][4] = {};
    gemm_mfma<4>(A_lds, WF3A, 16, wid * 4, lane, acc3);   // geo part
    gemm_mfma<4>(B_lds, WF23, 16, wid * 4, lane, acc3);   // h @ (W2@W3b)
    __syncthreads();                                      // drain all reads of A,B
    epilogue<4, true>(acc3, b3p, wid * 64, A_lds, wid * 64, lane);  // h2 -> A
  }
  __syncthreads();

  // ---- P4: out = h2 @ w_pred2 + b4 via MFMA (waves 0,1: rows m = wid; cols 4..15 junk)
  if (wid < 2) {
    f32x4 acc4 = {0.0f, 0.0f, 0.0f, 0.0f};
    const int arow = lane & 15;
    const int acol = (lane >> 4) << 3;
#pragma unroll
    for (int ks = 0; ks < 8; ++ks) {
      short8 a = *reinterpret_cast<const short8*>(&A_lds[swz(wid * 16 + arow, ks * 32 + acol)]);
      short8 b = WF4[ks * 64 + lane];
      acc4 = __builtin_amdgcn_mfma_f32_16x16x32_bf16(a, b, acc4, 0, 0, 0);
    }
    const int jlo = lane & 15;
    const int rhi = (lane >> 4) << 2;
    if (jlo < 4) {
      float bv = b4v[jlo];
#pragma unroll
      for (int t = 0; t < 4; ++t) {
        int g = row0 + wid * 16 + rhi + t;
        if (g < N) out[g * 4 + jlo] = acc4[t] + bv;
      }
    }
  }
}

extern "C" void kernel_launch(void* const* d_in, const int* in_sizes, int n_in,
                              void* d_out, int out_size, void* d_ws, size_t ws_size,
                              hipStream_t stream) {
  const float* grid  = (const float*)d_in[0];
  const float* sgrad = (const float*)d_in[1];
  const float* qpos  = (const float*)d_in[2];
  const float* quinf = (const float*)d_in[3];
  const float* qsdf  = (const float*)d_in[4];
  const float* qnrm  = (const float*)d_in[5];
  const float* qflow = (const float*)d_in[6];
  const float* w1 = (const float*)d_in[7];
  const float* b1 = (const float*)d_in[8];
  const float* w2 = (const float*)d_in[9];
  const float* b2 = (const float*)d_in[10];
  const float* w3 = (const float*)d_in[11];
  const float* b3 = (const float*)d_in[12];
  const float* w4 = (const float*)d_in[13];
  const float* b4 = (const float*)d_in[14];
  float* out = (float*)d_out;
  unsigned short* wsh = (unsigned short*)d_ws;

  const int N = in_sizes[2] / 2;  // 200000
  const bool hwc = ws_size >= WS_TOTAL_USHORTS * 2;

  if (hwc) {
    prep_fused<true><<<HW_GRID / 32 + 256, 256, 0, stream>>>(
        grid, w1, w2, w3, b2, b3, w4, wsh);
    fused_decoder<true><<<(N + ROWS - 1) / ROWS, 256, 0, stream>>>(
        grid, sgrad, qpos, quinf, qsdf, qnrm, qflow,
        b1, b4, wsh, out, N);
  } else {
    prep_fused<false><<<256, 256, 0, stream>>>(
        grid, w1, w2, w3, b2, b3, w4, wsh);
    fused_decoder<false><<<(N + ROWS - 1) / ROWS, 256, 0, stream>>>(
        grid, sgrad, qpos, quinf, qsdf, qnrm, qflow,
        b1, b4, wsh, out, N);
  }
}